// Round 17
// baseline (169.119 us; speedup 1.0000x reference)
//
#include <hip/hip_runtime.h>
#include <hip/hip_bf16.h>

// EnhancedSpatioTemporalLayer fused forward, round 17.
// Fused kernel restructured to 3 barriers: stage | conv | {k0 + small1 +
// small2 -> sZk1/sZk2} | {big1 + big2} -> bf16 tmp[(b,t)][o][n] (bf16x4
// stores, accb col=o row=n via operand swap). Transpose kernel (r16) emits
// out[b][o][n][t] with fused fp32 residual.

#define Bx   16
#define FINx 3
#define Nx   170
#define Tx   288
#define Hx   64
#define Ox   64
#define Kx   3
#define NP   192            // padded n/m (12 x 16)
#define XSW  10             // sXs row stride (bf16)
#define NBT  (Bx * Tx)      // 4608
#define TPAD 36             // transpose LDS t-stride (f32): 144B

#define CHEBF_ELEMS (Kx * 6 * 12 * 64 * 8)   // 110592: [sg=k*6+s][nt][lane][8]
#define THF_ELEMS   (Kx * 2 * 4 * 64 * 8)    // 12288:  [k][s][ot][lane][8]
#define WF_ELEMS    (4 * 64 * 8)             // 2048:   [ct][lane][8]
#define TMP_ELEMS   ((size_t)NBT * Ox * NP)  // 56,623,104 bf16 (~113 MB)
#define TMP_BYTES   (TMP_ELEMS * 2)

typedef __attribute__((ext_vector_type(8))) short bf16x8;
typedef __attribute__((ext_vector_type(4))) short bf16x4;
typedef __attribute__((ext_vector_type(4))) float f32x4;
typedef __attribute__((ext_vector_type(8))) short short8;

__device__ __align__(16) __hip_bfloat16 g_chebfrag[CHEBF_ELEMS];
__device__ __align__(16) __hip_bfloat16 g_thfrag[THF_ELEMS];
__device__ __align__(16) __hip_bfloat16 g_wfrag[WF_ELEMS];
__device__ __align__(16) __hip_bfloat16 g_tmp[TMP_ELEMS];   // fallback staging

static __device__ __forceinline__ short f2bf(float f) {
    __hip_bfloat16 h = __float2bfloat16(f);
    return *reinterpret_cast<short*>(&h);
}
static __device__ __forceinline__ float bf2f(short s) {
    __hip_bfloat16 h = *reinterpret_cast<__hip_bfloat16*>(&s);
    return __bfloat162float(h);
}

__global__ __launch_bounds__(512)
void precompute_frag(const float* __restrict__ cheb, const float* __restrict__ theta,
                     const float* __restrict__ conv_w, const float* __restrict__ conv_b) {
    int idx = blockIdx.x * 512 + threadIdx.x;
    if (idx < CHEBF_ELEMS) {
        int j = idx & 7, lane = (idx >> 3) & 63, rest = idx >> 9;
        int nt = rest % 12; rest /= 12;
        int s = rest % 6, k = rest / 6;
        int n = nt * 16 + (lane & 15);
        int m = s * 32 + (lane >> 4) * 8 + j;
        float v = (n < Nx && m < Nx) ? cheb[(k * Nx + n) * Nx + m] : 0.f;
        g_chebfrag[idx] = __float2bfloat16(v);
    } else if (idx < CHEBF_ELEMS + THF_ELEMS) {
        int jdx = idx - CHEBF_ELEMS;
        int j = jdx & 7, lane = (jdx >> 3) & 63, rest = jdx >> 9;
        int ot = rest % 4; rest /= 4;
        int s = rest % 2, k = rest / 2;
        int o = ot * 16 + (lane & 15);
        int c = s * 32 + (lane >> 4) * 8 + j;
        g_thfrag[jdx] = __float2bfloat16(theta[(k * Hx + c) * Ox + o]);
    } else if (idx < CHEBF_ELEMS + THF_ELEMS + WF_ELEMS) {
        int jdx = idx - CHEBF_ELEMS - THF_ELEMS;
        int j = jdx & 7, lane = (jdx >> 3) & 63, ct = jdx >> 9;
        int c = ct * 16 + (lane & 15);
        int slot = (lane >> 4) * 8 + j;
        float v = 0.f;
        if (slot < 9) v = conv_w[c * 9 + slot];
        else if (slot == 9) v = conv_b[c];
        g_wfrag[jdx] = __float2bfloat16(v);
    }
}

// XOR-swizzled LDS byte offsets (involution keyed on row&7)
static __device__ __forceinline__ int stm_off(int m, int byte) {      // 128B rows
    return m * 128 + (byte ^ ((m & 7) << 4));
}
static __device__ __forceinline__ int szk_off(int o, int byte) {      // 384B rows
    return o * 384 + (byte ^ ((o & 7) << 4));
}

__global__ __launch_bounds__(512, 4)
void stgcn_fused10(const float* __restrict__ x,
                   __hip_bfloat16* __restrict__ tmp) {
    __shared__ __align__(16) char sTm[NP * 128];            // 24.0 KB (swizzled)
    __shared__ __align__(16) char sZk1[Ox * 384];           // 24.0 KB (swizzled)
    __shared__ __align__(16) char sZk2[Ox * 384];           // 24.0 KB (swizzled)
    __shared__ __hip_bfloat16 sXs[NP * XSW];                // 3.75 KB

    const int tid = threadIdx.x;
    const int vid = (blockIdx.x & 7) * 576 + (blockIdx.x >> 3);  // XCD-chunked swizzle
    const int b  = vid / Tx;
    const int t0 = vid % Tx;

    // ---- stage x slice [192][10] bf16 (zeros outside 170 rows / 9 cols) ----
    for (int idx = tid; idx < NP * XSW; idx += 512) {
        int n = idx / XSW, r = idx % XSW;
        float v = 0.f;
        if (n < Nx && r < 9) {
            int f = r / 3, j = r % 3;
            int tt = t0 - 1 + j;
            if (tt >= 0 && tt < Tx) v = x[((b * FINx + f) * Nx + n) * Tx + tt];
        }
        sXs[idx] = __float2bfloat16(v);
    }

    const int lane = tid & 63;
    const int w    = tid >> 6;
    const int l16  = lane & 15;
    const int lk   = lane >> 4;

    const int mg = w & 3;        // conv/small GEMM: m-tiles mg*3+j (j=0..2)
    const int og = w >> 2;       // conv/small GEMM: o/c-tiles og*2+u (u=0..1)
    const int wr = w & 1;        // k0/big GEMM: o-tiles wr*2+oi (oi=0..1)
    const int wc = w >> 1;       // k0/big GEMM: n-tiles wc*3+nj (nj=0..2)

    __syncthreads();             // (1) sXs staged

    // ---- conv via MFMA: Tm[m][c] = relu(Xp @ Wf) (bias in slot 9) ----
    {
        bf16x8 wfr[2], xfr[3];
#pragma unroll
        for (int u = 0; u < 2; ++u)
            wfr[u] = *(const bf16x8*)(&g_wfrag[((og * 2 + u) * 64 + lane) * 8]);
#pragma unroll
        for (int j = 0; j < 3; ++j) {
            int m = (mg * 3 + j) * 16 + l16;
            bf16x8 xf;
#pragma unroll
            for (int q = 0; q < 8; ++q) xf[q] = 0;
            if (lk == 0) {
#pragma unroll
                for (int q = 0; q < 8; ++q)
                    xf[q] = *reinterpret_cast<const short*>(&sXs[m * XSW + q]);
            } else if (lk == 1) {
                xf[0] = *reinterpret_cast<const short*>(&sXs[m * XSW + 8]);
                xf[1] = f2bf(1.0f);           // slot 9 = bias
            }
            xfr[j] = xf;
        }
#pragma unroll
        for (int j = 0; j < 3; ++j)
#pragma unroll
            for (int u = 0; u < 2; ++u) {
                f32x4 tacc = (f32x4)0.f;
                tacc = __builtin_amdgcn_mfma_f32_16x16x32_bf16(wfr[u], xfr[j], tacc, 0, 0, 0);
                int m  = (mg * 3 + j) * 16 + l16;
                int c0 = (og * 2 + u) * 16 + lk * 4;
                bf16x4 v;
#pragma unroll
                for (int r = 0; r < 4; ++r) v[r] = f2bf(fmaxf(tacc[r], 0.f));
                *(bf16x4*)(sTm + stm_off(m, c0 * 2)) = v;
            }
    }
    __syncthreads();             // (2) sTm ready

    f32x4 accb[2][3];            // persistent accumulator: col=o(l16), row=n(lk*4+r)
#pragma unroll
    for (int oi = 0; oi < 2; ++oi)
#pragma unroll
        for (int nj = 0; nj < 3; ++nj) accb[oi][nj] = (f32x4)0.f;

    // ---- phase A: k0 identity + both small GEMMs (all read only sTm) ----
    // k0 (cheb_0 = I): accb += mfma(A=Tm(n-rows), B=theta0(o-rows)) -> col=o,row=n
#pragma unroll
    for (int s = 0; s < 2; ++s) {
        bf16x8 tf[2], nf[3];
#pragma unroll
        for (int oi = 0; oi < 2; ++oi)
            tf[oi] = *(const bf16x8*)(&g_thfrag[((s * 4 + wr * 2 + oi) * 64 + lane) * 8]);
#pragma unroll
        for (int nj = 0; nj < 3; ++nj) {
            int n = (wc * 3 + nj) * 16 + l16;
            nf[nj] = *(const bf16x8*)(sTm + stm_off(n, s * 64 + lk * 16));
        }
#pragma unroll
        for (int oi = 0; oi < 2; ++oi)
#pragma unroll
            for (int nj = 0; nj < 3; ++nj)
                accb[oi][nj] = __builtin_amdgcn_mfma_f32_16x16x32_bf16(
                    nf[nj], tf[oi], accb[oi][nj], 0, 0, 0);
    }

    // small GEMMs: Z_k[m][o] = Tm @ theta_k -> sZk{1,2}[o][m] (swizzled)
#pragma unroll
    for (int k = 1; k < Kx; ++k) {
        char* zbuf = (k == 1) ? sZk1 : sZk2;
        f32x4 accs[3][2];
#pragma unroll
        for (int j = 0; j < 3; ++j)
#pragma unroll
            for (int u = 0; u < 2; ++u) accs[j][u] = (f32x4)0.f;

#pragma unroll
        for (int s = 0; s < 2; ++s) {
            bf16x8 afr[3], bfr[2];
#pragma unroll
            for (int j = 0; j < 3; ++j) {
                int m = (mg * 3 + j) * 16 + l16;
                afr[j] = *(const bf16x8*)(sTm + stm_off(m, s * 64 + lk * 16));
            }
#pragma unroll
            for (int u = 0; u < 2; ++u)
                bfr[u] = *(const bf16x8*)(&g_thfrag[
                         ((((k * 2 + s) * 4) + og * 2 + u) * 64 + lane) * 8]);
#pragma unroll
            for (int j = 0; j < 3; ++j)
#pragma unroll
                for (int u = 0; u < 2; ++u)
                    accs[j][u] = __builtin_amdgcn_mfma_f32_16x16x32_bf16(
                        afr[j], bfr[u], accs[j][u], 0, 0, 0);
        }
#pragma unroll
        for (int j = 0; j < 3; ++j)
#pragma unroll
            for (int u = 0; u < 2; ++u) {
                int o  = (og * 2 + u) * 16 + l16;
                int m0 = (mg * 3 + j) * 16 + lk * 4;
                bf16x4 v;
#pragma unroll
                for (int r = 0; r < 4; ++r) v[r] = f2bf(accs[j][u][r]);
                *(bf16x4*)(zbuf + szk_off(o, m0 * 2)) = v;
            }
    }
    __syncthreads();             // (3) sZk1/sZk2 ready

    // ---- phase B: big GEMMs k=1,2: accb += mfma(A=cheb(n), B=Z(o)) ----
#pragma unroll
    for (int k = 1; k < Kx; ++k) {
        const char* zbuf = (k == 1) ? sZk1 : sZk2;
#pragma unroll
        for (int s = 0; s < 6; ++s) {
            bf16x8 zfr[2], cfr[3];
#pragma unroll
            for (int oi = 0; oi < 2; ++oi) {
                int o = (wr * 2 + oi) * 16 + l16;
                zfr[oi] = *(const bf16x8*)(zbuf + szk_off(o, s * 64 + lk * 16));
            }
#pragma unroll
            for (int nj = 0; nj < 3; ++nj)
                cfr[nj] = *(const bf16x8*)(&g_chebfrag[
                          ((((k * 6 + s) * 12) + wc * 3 + nj) * 64 + lane) * 8]);
#pragma unroll
            for (int oi = 0; oi < 2; ++oi)
#pragma unroll
                for (int nj = 0; nj < 3; ++nj)
                    accb[oi][nj] = __builtin_amdgcn_mfma_f32_16x16x32_bf16(
                        cfr[nj], zfr[oi], accb[oi][nj], 0, 0, 0);
        }
    }

    // ---- epilogue: relu(gcn) -> bf16 tmp[(b,t0)][o][n], bf16x4 stores ----
    __hip_bfloat16* tbase = tmp + ((size_t)b * Tx + t0) * (Ox * NP);
#pragma unroll
    for (int oi = 0; oi < 2; ++oi) {
        int o = (wr * 2 + oi) * 16 + l16;
#pragma unroll
        for (int nj = 0; nj < 3; ++nj) {
            int n0 = (wc * 3 + nj) * 16 + lk * 4;
            bf16x4 v;
#pragma unroll
            for (int r = 0; r < 4; ++r)
                v[r] = f2bf(fmaxf(accb[oi][nj][r], 0.f));
            *(bf16x4*)(tbase + (size_t)o * NP + n0) = v;
        }
    }
}

// ---- transpose + residual: tmp[(b,t)][o][n] bf16 -> out[b][o][n][t] f32 ----
__global__ __launch_bounds__(256, 4)
void transpose_res(const __hip_bfloat16* __restrict__ tmp,
                   const float* __restrict__ x,
                   const float* __restrict__ res_w,
                   const float* __restrict__ res_b,
                   float* __restrict__ out) {
    __shared__ float sT[NP * TPAD];   // 27.6 KB

    const int bid = blockIdx.x;       // 9216 = 16 * 64 * 9
    const int tt  = bid % 9;
    const int o   = (bid / 9) & 63;
    const int b   = bid / (9 * 64);
    const int t0  = tt * 32;
    const int tid = threadIdx.x;

    const float rw0 = res_w[o * 3 + 0], rw1 = res_w[o * 3 + 1], rw2 = res_w[o * 3 + 2];
    const float rb  = res_b[o];

    const __hip_bfloat16* src = tmp + (((size_t)b * Tx + t0) * Ox + o) * NP;
    {
        const int t  = tid >> 3;              // 0..31
        const int n8 = (tid & 7) * 8;
        const __hip_bfloat16* s = src + (size_t)t * (Ox * NP);
#pragma unroll
        for (int i = 0; i < 3; ++i) {
            int n0 = n8 + i * 64;
            short8 v = *(const short8*)(s + n0);
#pragma unroll
            for (int e = 0; e < 8; ++e) {
                int n  = n0 + e;
                int tc = t ^ ((n & 7) * 4);   // XOR swizzle, bijective in t
                sT[n * TPAD + tc] = bf2f(v[e]);
            }
        }
    }
    __syncthreads();
    {
        const int q  = tid & 7;               // t-quad
        const int nr = tid >> 3;              // 0..31
        const float* xb = x + (size_t)(b * FINx) * Nx * Tx + t0 + q * 4;
#pragma unroll
        for (int j = 0; j < 6; ++j) {
            int n = nr + j * 32;
            if (n < Nx) {
                int tc4 = (q ^ (n & 7)) * 4;  // de-swizzled float4 column
                float4 g = *(const float4*)(&sT[n * TPAD + tc4]);
                float4 x0 = *(const float4*)(xb + (size_t)(0 * Nx + n) * Tx);
                float4 x1 = *(const float4*)(xb + (size_t)(1 * Nx + n) * Tx);
                float4 x2 = *(const float4*)(xb + (size_t)(2 * Nx + n) * Tx);
                float4 wv;
                wv.x = g.x + rb + x0.x * rw0 + x1.x * rw1 + x2.x * rw2;
                wv.y = g.y + rb + x0.y * rw0 + x1.y * rw1 + x2.y * rw2;
                wv.z = g.z + rb + x0.z * rw0 + x1.z * rw1 + x2.z * rw2;
                wv.w = g.w + rb + x0.w * rw0 + x1.w * rw1 + x2.w * rw2;
                *(float4*)(&out[((size_t)(b * Ox + o) * Nx + n) * Tx + t0 + q * 4]) = wv;
            }
        }
    }
}

extern "C" void kernel_launch(void* const* d_in, const int* in_sizes, int n_in,
                              void* d_out, int out_size, void* d_ws, size_t ws_size,
                              hipStream_t stream) {
    const float* x      = (const float*)d_in[0];
    const float* cheb   = (const float*)d_in[2];
    const float* conv_w = (const float*)d_in[3];
    const float* conv_b = (const float*)d_in[4];
    const float* theta  = (const float*)d_in[5];
    const float* res_w  = (const float*)d_in[6];
    const float* res_b  = (const float*)d_in[7];
    float* out = (float*)d_out;

    __hip_bfloat16* tmp;
    if (ws_size >= TMP_BYTES) {
        tmp = (__hip_bfloat16*)d_ws;
    } else {
        void* sym = nullptr;
        hipGetSymbolAddress(&sym, HIP_SYMBOL(g_tmp));
        tmp = (__hip_bfloat16*)sym;
    }

    int pre_elems = CHEBF_ELEMS + THF_ELEMS + WF_ELEMS;
    hipLaunchKernelGGL(precompute_frag, dim3((pre_elems + 511) / 512), dim3(512), 0, stream,
                       cheb, theta, conv_w, conv_b);
    hipLaunchKernelGGL(stgcn_fused10, dim3(NBT), dim3(512), 0, stream, x, tmp);
    hipLaunchKernelGGL(transpose_res, dim3(Bx * Ox * 9), dim3(256), 0, stream,
                       tmp, x, res_w, res_b, out);
}

// Round 18
// 158.669 us; speedup vs baseline: 1.0659x; 1.0659x over previous
//
#include <hip/hip_runtime.h>
#include <hip/hip_bf16.h>

// EnhancedSpatioTemporalLayer fused forward, round 18.
// Round-16 structure EXACTLY, with one change: sXs aliases the head of sZk
// (sXs is dead after the conv phase; sZk first written after the next
// barrier). LDS 53.2 -> 48.0 KB => 3 blocks/CU (24 waves, 3 barrier domains).
// Fused: conv-MFMA + k0-identity + k=1,2 GEMMs -> relu(gcn) bf16 to
// tmp[(b,t)][o][n]; transpose kernel emits out[b][o][n][t] + fp32 residual.

#define Bx   16
#define FINx 3
#define Nx   170
#define Tx   288
#define Hx   64
#define Ox   64
#define Kx   3
#define NP   192            // padded n/m (12 x 16)
#define XSW  10             // sXs row stride (bf16)
#define NBT  (Bx * Tx)      // 4608
#define TPAD 36             // transpose LDS t-stride (f32): 144B

#define CHEBF_ELEMS (Kx * 6 * 12 * 64 * 8)   // 110592: [sg=k*6+s][nt][lane][8]
#define THF_ELEMS   (Kx * 2 * 4 * 64 * 8)    // 12288:  [k][s][ot][lane][8]
#define WF_ELEMS    (4 * 64 * 8)             // 2048:   [ct][lane][8]
#define TMP_ELEMS   ((size_t)NBT * Ox * NP)  // 56,623,104 bf16 (~113 MB)
#define TMP_BYTES   (TMP_ELEMS * 2)

typedef __attribute__((ext_vector_type(8))) short bf16x8;
typedef __attribute__((ext_vector_type(4))) short bf16x4;
typedef __attribute__((ext_vector_type(4))) float f32x4;
typedef __attribute__((ext_vector_type(8))) short short8;

__device__ __align__(16) __hip_bfloat16 g_chebfrag[CHEBF_ELEMS];
__device__ __align__(16) __hip_bfloat16 g_thfrag[THF_ELEMS];
__device__ __align__(16) __hip_bfloat16 g_wfrag[WF_ELEMS];
__device__ __align__(16) __hip_bfloat16 g_tmp[TMP_ELEMS];   // fallback staging

static __device__ __forceinline__ short f2bf(float f) {
    __hip_bfloat16 h = __float2bfloat16(f);
    return *reinterpret_cast<short*>(&h);
}
static __device__ __forceinline__ float bf2f(short s) {
    __hip_bfloat16 h = *reinterpret_cast<__hip_bfloat16*>(&s);
    return __bfloat162float(h);
}

__global__ __launch_bounds__(512)
void precompute_frag(const float* __restrict__ cheb, const float* __restrict__ theta,
                     const float* __restrict__ conv_w, const float* __restrict__ conv_b) {
    int idx = blockIdx.x * 512 + threadIdx.x;
    if (idx < CHEBF_ELEMS) {
        int j = idx & 7, lane = (idx >> 3) & 63, rest = idx >> 9;
        int nt = rest % 12; rest /= 12;
        int s = rest % 6, k = rest / 6;
        int n = nt * 16 + (lane & 15);
        int m = s * 32 + (lane >> 4) * 8 + j;
        float v = (n < Nx && m < Nx) ? cheb[(k * Nx + n) * Nx + m] : 0.f;
        g_chebfrag[idx] = __float2bfloat16(v);
    } else if (idx < CHEBF_ELEMS + THF_ELEMS) {
        int jdx = idx - CHEBF_ELEMS;
        int j = jdx & 7, lane = (jdx >> 3) & 63, rest = jdx >> 9;
        int ot = rest % 4; rest /= 4;
        int s = rest % 2, k = rest / 2;
        int o = ot * 16 + (lane & 15);
        int c = s * 32 + (lane >> 4) * 8 + j;
        g_thfrag[jdx] = __float2bfloat16(theta[(k * Hx + c) * Ox + o]);
    } else if (idx < CHEBF_ELEMS + THF_ELEMS + WF_ELEMS) {
        int jdx = idx - CHEBF_ELEMS - THF_ELEMS;
        int j = jdx & 7, lane = (jdx >> 3) & 63, ct = jdx >> 9;
        int c = ct * 16 + (lane & 15);
        int slot = (lane >> 4) * 8 + j;
        float v = 0.f;
        if (slot < 9) v = conv_w[c * 9 + slot];
        else if (slot == 9) v = conv_b[c];
        g_wfrag[jdx] = __float2bfloat16(v);
    }
}

// XOR-swizzled LDS byte offsets (involution keyed on row&7)
static __device__ __forceinline__ int stm_off(int m, int byte) {      // 128B rows
    return m * 128 + (byte ^ ((m & 7) << 4));
}
static __device__ __forceinline__ int szk_off(int o, int byte) {      // 384B rows
    return o * 384 + (byte ^ ((o & 7) << 4));
}

__global__ __launch_bounds__(512, 4)
void stgcn_fused11(const float* __restrict__ x,
                   __hip_bfloat16* __restrict__ tmp) {
    __shared__ __align__(16) char sTm[NP * 128];            // 24.0 KB (swizzled)
    __shared__ __align__(16) char sZk[Ox * 384];            // 24.0 KB (swizzled)
    // sXs aliases sZk's head: read only in stage+conv phases; sZk first
    // written after the post-conv barrier. Saves 3.75 KB -> 48 KB total.
    __hip_bfloat16* const sXs = (__hip_bfloat16*)sZk;

    const int tid = threadIdx.x;
    const int vid = (blockIdx.x & 7) * 576 + (blockIdx.x >> 3);  // XCD-chunked swizzle
    const int b  = vid / Tx;
    const int t0 = vid % Tx;

    // ---- stage x slice [192][10] bf16 (zeros outside 170 rows / 9 cols) ----
    for (int idx = tid; idx < NP * XSW; idx += 512) {
        int n = idx / XSW, r = idx % XSW;
        float v = 0.f;
        if (n < Nx && r < 9) {
            int f = r / 3, j = r % 3;
            int tt = t0 - 1 + j;
            if (tt >= 0 && tt < Tx) v = x[((b * FINx + f) * Nx + n) * Tx + tt];
        }
        sXs[idx] = __float2bfloat16(v);
    }

    const int lane = tid & 63;
    const int w    = tid >> 6;
    const int l16  = lane & 15;
    const int lk   = lane >> 4;

    const int mg = w & 3;        // conv/small GEMM: m-tiles mg*3+j (j=0..2)
    const int og = w >> 2;       // conv/small GEMM: o/c-tiles og*2+u (u=0..1)
    const int wr = w & 1;        // big GEMM: o-tiles wr*2+oi (oi=0..1)
    const int wc = w >> 1;       // big GEMM: n-tiles wc*3+nj (nj=0..2)

    __syncthreads();

    // ---- conv via MFMA: Tm[m][c] = relu(Xp @ Wf) (bias in slot 9) ----
    {
        bf16x8 wfr[2], xfr[3];
#pragma unroll
        for (int u = 0; u < 2; ++u)
            wfr[u] = *(const bf16x8*)(&g_wfrag[((og * 2 + u) * 64 + lane) * 8]);
#pragma unroll
        for (int j = 0; j < 3; ++j) {
            int m = (mg * 3 + j) * 16 + l16;
            bf16x8 xf;
#pragma unroll
            for (int q = 0; q < 8; ++q) xf[q] = 0;
            if (lk == 0) {
#pragma unroll
                for (int q = 0; q < 8; ++q)
                    xf[q] = *reinterpret_cast<const short*>(&sXs[m * XSW + q]);
            } else if (lk == 1) {
                xf[0] = *reinterpret_cast<const short*>(&sXs[m * XSW + 8]);
                xf[1] = f2bf(1.0f);           // slot 9 = bias
            }
            xfr[j] = xf;
        }
#pragma unroll
        for (int j = 0; j < 3; ++j)
#pragma unroll
            for (int u = 0; u < 2; ++u) {
                f32x4 tacc = (f32x4)0.f;
                tacc = __builtin_amdgcn_mfma_f32_16x16x32_bf16(wfr[u], xfr[j], tacc, 0, 0, 0);
                int m  = (mg * 3 + j) * 16 + l16;
                int c0 = (og * 2 + u) * 16 + lk * 4;
                bf16x4 v;
#pragma unroll
                for (int r = 0; r < 4; ++r) v[r] = f2bf(fmaxf(tacc[r], 0.f));
                *(bf16x4*)(sTm + stm_off(m, c0 * 2)) = v;
            }
    }
    __syncthreads();             // conv done; sXs now dead -> sZk may be written

    f32x4 accb[2][3];            // persistent GT accumulator [oi][nj]
#pragma unroll
    for (int oi = 0; oi < 2; ++oi)
#pragma unroll
        for (int nj = 0; nj < 3; ++nj) accb[oi][nj] = (f32x4)0.f;

    // ---- k=0 (cheb_0 = I): accb += mfma(theta0(o-rows), Tm(n-rows)) ----
#pragma unroll
    for (int s = 0; s < 2; ++s) {
        bf16x8 tf[2], nf[3];
#pragma unroll
        for (int oi = 0; oi < 2; ++oi)
            tf[oi] = *(const bf16x8*)(&g_thfrag[((s * 4 + wr * 2 + oi) * 64 + lane) * 8]);
#pragma unroll
        for (int nj = 0; nj < 3; ++nj) {
            int n = (wc * 3 + nj) * 16 + l16;
            nf[nj] = *(const bf16x8*)(sTm + stm_off(n, s * 64 + lk * 16));
        }
#pragma unroll
        for (int oi = 0; oi < 2; ++oi)
#pragma unroll
            for (int nj = 0; nj < 3; ++nj)
                accb[oi][nj] = __builtin_amdgcn_mfma_f32_16x16x32_bf16(tf[oi], nf[nj], accb[oi][nj], 0, 0, 0);
    }

    // ---- k = 1, 2 ----
    for (int k = 1; k < Kx; ++k) {
        __syncthreads();

        f32x4 accs[3][2];
#pragma unroll
        for (int j = 0; j < 3; ++j)
#pragma unroll
            for (int u = 0; u < 2; ++u) accs[j][u] = (f32x4)0.f;

#pragma unroll
        for (int s = 0; s < 2; ++s) {
            bf16x8 afr[3], bfr[2];
#pragma unroll
            for (int j = 0; j < 3; ++j) {
                int m = (mg * 3 + j) * 16 + l16;
                afr[j] = *(const bf16x8*)(sTm + stm_off(m, s * 64 + lk * 16));
            }
#pragma unroll
            for (int u = 0; u < 2; ++u)
                bfr[u] = *(const bf16x8*)(&g_thfrag[
                         ((((k * 2 + s) * 4) + og * 2 + u) * 64 + lane) * 8]);
#pragma unroll
            for (int j = 0; j < 3; ++j)
#pragma unroll
                for (int u = 0; u < 2; ++u)
                    accs[j][u] = __builtin_amdgcn_mfma_f32_16x16x32_bf16(afr[j], bfr[u], accs[j][u], 0, 0, 0);
        }
#pragma unroll
        for (int j = 0; j < 3; ++j)
#pragma unroll
            for (int u = 0; u < 2; ++u) {
                int o  = (og * 2 + u) * 16 + l16;
                int m0 = (mg * 3 + j) * 16 + lk * 4;
                bf16x4 v;
#pragma unroll
                for (int r = 0; r < 4; ++r) v[r] = f2bf(accs[j][u][r]);
                *(bf16x4*)(sZk + szk_off(o, m0 * 2)) = v;
            }
        __syncthreads();

#pragma unroll
        for (int s = 0; s < 6; ++s) {
            bf16x8 afr2[2], bfr2[3];
#pragma unroll
            for (int oi = 0; oi < 2; ++oi) {
                int o = (wr * 2 + oi) * 16 + l16;
                afr2[oi] = *(const bf16x8*)(sZk + szk_off(o, s * 64 + lk * 16));
            }
#pragma unroll
            for (int nj = 0; nj < 3; ++nj)
                bfr2[nj] = *(const bf16x8*)(&g_chebfrag[
                           ((((k * 6 + s) * 12) + wc * 3 + nj) * 64 + lane) * 8]);
#pragma unroll
            for (int oi = 0; oi < 2; ++oi)
#pragma unroll
                for (int nj = 0; nj < 3; ++nj)
                    accb[oi][nj] = __builtin_amdgcn_mfma_f32_16x16x32_bf16(afr2[oi], bfr2[nj], accb[oi][nj], 0, 0, 0);
        }
    }

    // ---- epilogue: relu(gcn) -> bf16 tmp[(b,t0)][o][n] (n lane-minor) ----
    __hip_bfloat16* tbase = tmp + ((size_t)b * Tx + t0) * (Ox * NP);
#pragma unroll
    for (int nj = 0; nj < 3; ++nj) {
        int n = (wc * 3 + nj) * 16 + l16;
#pragma unroll
        for (int oi = 0; oi < 2; ++oi) {
#pragma unroll
            for (int r = 0; r < 4; ++r) {
                int o = (wr * 2 + oi) * 16 + lk * 4 + r;
                tbase[(size_t)o * NP + n] = __float2bfloat16(fmaxf(accb[oi][nj][r], 0.f));
            }
        }
    }
}

// ---- transpose + residual: tmp[(b,t)][o][n] bf16 -> out[b][o][n][t] f32 ----
__global__ __launch_bounds__(256, 4)
void transpose_res(const __hip_bfloat16* __restrict__ tmp,
                   const float* __restrict__ x,
                   const float* __restrict__ res_w,
                   const float* __restrict__ res_b,
                   float* __restrict__ out) {
    __shared__ float sT[NP * TPAD];   // 27.6 KB

    const int bid = blockIdx.x;       // 9216 = 16 * 64 * 9
    const int tt  = bid % 9;
    const int o   = (bid / 9) & 63;
    const int b   = bid / (9 * 64);
    const int t0  = tt * 32;
    const int tid = threadIdx.x;

    const float rw0 = res_w[o * 3 + 0], rw1 = res_w[o * 3 + 1], rw2 = res_w[o * 3 + 2];
    const float rb  = res_b[o];

    const __hip_bfloat16* src = tmp + (((size_t)b * Tx + t0) * Ox + o) * NP;
    {
        const int t  = tid >> 3;              // 0..31
        const int n8 = (tid & 7) * 8;
        const __hip_bfloat16* s = src + (size_t)t * (Ox * NP);
#pragma unroll
        for (int i = 0; i < 3; ++i) {
            int n0 = n8 + i * 64;
            short8 v = *(const short8*)(s + n0);
#pragma unroll
            for (int e = 0; e < 8; ++e) {
                int n  = n0 + e;
                int tc = t ^ ((n & 7) * 4);   // XOR swizzle, bijective in t
                sT[n * TPAD + tc] = bf2f(v[e]);
            }
        }
    }
    __syncthreads();
    {
        const int q  = tid & 7;               // t-quad
        const int nr = tid >> 3;              // 0..31
        const float* xb = x + (size_t)(b * FINx) * Nx * Tx + t0 + q * 4;
#pragma unroll
        for (int j = 0; j < 6; ++j) {
            int n = nr + j * 32;
            if (n < Nx) {
                int tc4 = (q ^ (n & 7)) * 4;  // de-swizzled float4 column
                float4 g = *(const float4*)(&sT[n * TPAD + tc4]);
                float4 x0 = *(const float4*)(xb + (size_t)(0 * Nx + n) * Tx);
                float4 x1 = *(const float4*)(xb + (size_t)(1 * Nx + n) * Tx);
                float4 x2 = *(const float4*)(xb + (size_t)(2 * Nx + n) * Tx);
                float4 wv;
                wv.x = g.x + rb + x0.x * rw0 + x1.x * rw1 + x2.x * rw2;
                wv.y = g.y + rb + x0.y * rw0 + x1.y * rw1 + x2.y * rw2;
                wv.z = g.z + rb + x0.z * rw0 + x1.z * rw1 + x2.z * rw2;
                wv.w = g.w + rb + x0.w * rw0 + x1.w * rw1 + x2.w * rw2;
                *(float4*)(&out[((size_t)(b * Ox + o) * Nx + n) * Tx + t0 + q * 4]) = wv;
            }
        }
    }
}

extern "C" void kernel_launch(void* const* d_in, const int* in_sizes, int n_in,
                              void* d_out, int out_size, void* d_ws, size_t ws_size,
                              hipStream_t stream) {
    const float* x      = (const float*)d_in[0];
    const float* cheb   = (const float*)d_in[2];
    const float* conv_w = (const float*)d_in[3];
    const float* conv_b = (const float*)d_in[4];
    const float* theta  = (const float*)d_in[5];
    const float* res_w  = (const float*)d_in[6];
    const float* res_b  = (const float*)d_in[7];
    float* out = (float*)d_out;

    __hip_bfloat16* tmp;
    if (ws_size >= TMP_BYTES) {
        tmp = (__hip_bfloat16*)d_ws;
    } else {
        void* sym = nullptr;
        hipGetSymbolAddress(&sym, HIP_SYMBOL(g_tmp));
        tmp = (__hip_bfloat16*)sym;
    }

    int pre_elems = CHEBF_ELEMS + THF_ELEMS + WF_ELEMS;
    hipLaunchKernelGGL(precompute_frag, dim3((pre_elems + 511) / 512), dim3(512), 0, stream,
                       cheb, theta, conv_w, conv_b);
    hipLaunchKernelGGL(stgcn_fused11, dim3(NBT), dim3(512), 0, stream, x, tmp);
    hipLaunchKernelGGL(transpose_res, dim3(Bx * Ox * 9), dim3(256), 0, stream,
                       tmp, x, res_w, res_b, out);
}